// Round 1
// baseline (50.503 us; speedup 1.0000x reference)
//
#include <hip/hip_runtime.h>
#include <float.h>

#define B_    64
#define C_    1000
#define HW_   784
#define TOPK_ 25

// Kernel 1: per-batch top-25 argmax of main_out + per-batch sum of p.
// One block per batch row.
__global__ void topk_psum_kernel(const float* __restrict__ p,
                                 const float* __restrict__ main_out,
                                 int* __restrict__ idx_out,
                                 float* __restrict__ psum_out) {
    const int b   = blockIdx.x;
    const int tid = threadIdx.x;
    const int nt  = blockDim.x;

    __shared__ float vals[C_];
    for (int i = tid; i < C_; i += nt)
        vals[i] = main_out[b * C_ + i];
    __syncthreads();

    __shared__ float red_v[256];
    __shared__ int   red_i[256];

    for (int k = 0; k < TOPK_; ++k) {
        // per-thread strided scan; strict '>' keeps smallest index on ties
        float best = -FLT_MAX;
        int   bi   = 0x7fffffff;
        for (int i = tid; i < C_; i += nt) {
            float v = vals[i];
            if (v > best) { best = v; bi = i; }
        }
        red_v[tid] = best;
        red_i[tid] = bi;
        __syncthreads();
        for (int s = nt >> 1; s > 0; s >>= 1) {
            if (tid < s) {
                float ov = red_v[tid + s];
                int   oi = red_i[tid + s];
                if (ov > red_v[tid] || (ov == red_v[tid] && oi < red_i[tid])) {
                    red_v[tid] = ov;
                    red_i[tid] = oi;
                }
            }
            __syncthreads();
        }
        if (tid == 0) {
            int sel = red_i[0];
            idx_out[b * TOPK_ + k] = sel;
            vals[sel] = -FLT_MAX;   // exclude from later rounds
        }
        __syncthreads();
    }

    // sum p[b, 0, :, :] (784 floats)
    const float* pb = p + (size_t)b * HW_;
    double local = 0.0;
    for (int i = tid; i < HW_; i += nt) local += (double)pb[i];

    __shared__ double dred[256];
    dred[tid] = local;
    __syncthreads();
    for (int s = nt >> 1; s > 0; s >>= 1) {
        if (tid < s) dred[tid] += dred[tid + s];
        __syncthreads();
    }
    if (tid == 0) psum_out[b] = (float)dred[0];
}

// Kernel 2: one block per (b, k): sum features[b, idx[b,k], :, :]
__global__ void gather_sum_kernel(const float* __restrict__ features,
                                  const int* __restrict__ idx,
                                  float* __restrict__ fsum) {
    const int g   = blockIdx.x;        // 0 .. B_*TOPK_-1
    const int b   = g / TOPK_;
    const int c   = idx[g];
    const int tid = threadIdx.x;
    const int nt  = blockDim.x;

    const float* f = features + ((size_t)b * C_ + (size_t)c) * HW_;
    float local = 0.0f;
    for (int i = tid; i < HW_; i += nt) local += f[i];

    __shared__ float red[256];
    red[tid] = local;
    __syncthreads();
    for (int s = nt >> 1; s > 0; s >>= 1) {
        if (tid < s) red[tid] += red[tid + s];
        __syncthreads();
    }
    if (tid == 0) fsum[g] = red[0];
}

// Kernel 3: final reduction -> scalar
__global__ void finalize_kernel(const float* __restrict__ psum,
                                const float* __restrict__ fsum,
                                float* __restrict__ out) {
    const int tid = threadIdx.x;
    const int nt  = blockDim.x;

    double local = 0.0;
    for (int i = tid; i < B_; i += nt)          local += (double)psum[i];
    for (int i = tid; i < B_ * TOPK_; i += nt)  local += (double)fsum[i];

    __shared__ double red[256];
    red[tid] = local;
    __syncthreads();
    for (int s = nt >> 1; s > 0; s >>= 1) {
        if (tid < s) red[tid] += red[tid + s];
        __syncthreads();
    }
    if (tid == 0) out[0] = (float)(red[0] / (double)(B_ * HW_));
}

extern "C" void kernel_launch(void* const* d_in, const int* in_sizes, int n_in,
                              void* d_out, int out_size, void* d_ws, size_t ws_size,
                              hipStream_t stream) {
    const float* p        = (const float*)d_in[0];   // [64,1,28,28]
    const float* main_out = (const float*)d_in[1];   // [64,1000]
    const float* features = (const float*)d_in[2];   // [64,1000,28,28]
    float*       out      = (float*)d_out;           // scalar

    // workspace layout: idx[B*K] ints | psum[B] floats | fsum[B*K] floats
    int*   idx  = (int*)d_ws;
    float* psum = (float*)((char*)d_ws + (size_t)B_ * TOPK_ * sizeof(int));
    float* fsum = psum + B_;

    topk_psum_kernel<<<B_, 256, 0, stream>>>(p, main_out, idx, psum);
    gather_sum_kernel<<<B_ * TOPK_, 256, 0, stream>>>(features, idx, fsum);
    finalize_kernel<<<1, 256, 0, stream>>>(psum, fsum, out);
}